// Round 13
// baseline (220.168 us; speedup 1.0000x reference)
//
#include <hip/hip_runtime.h>
#include <math.h>

#define N_NODES 50000
#define N_EDGES 1600000
#define NFEAT 256
#define NHID 64
#define NCLASS 16

#define PBITS 7
#define PNODES 128                       // nodes per bin
#define NBINS ((N_NODES + PNODES - 1) / PNODES)   // 391
#define BIN_CAP 5120                     // mean 4092, sigma 64 -> +16 sigma
#define K3_CHUNK 4096
#define K3_PER_T 16                      // 4096 / 256
#define K3_BLOCKS ((N_EDGES + K3_CHUNK - 1) / K3_CHUNK)  // 391

__device__ inline unsigned short f2bf(float f) {     // RNE f32 -> bf16
    unsigned u = __float_as_uint(f);
    return (unsigned short)((u + 0x7FFFu + ((u >> 16) & 1u)) >> 16);
}

// ======================= counting-sort CSR build ===========================

__global__ void init_cursor_kernel(int* __restrict__ bin_cursor) {
    int b = blockIdx.x * 256 + threadIdx.x;
    if (b < NBINS) bin_cursor[b] = b * BIN_CAP;
}

// K3: per-block local counting sort by bin -> bin-grouped csr_bin.
// Wave-privatized histograms/cursors (4 waves): LDS atomic contention /4.
__global__ __launch_bounds__(256) void bin_scatter_kernel(
        const int* __restrict__ src, const int* __restrict__ dst,
        const float* __restrict__ w, int* __restrict__ bin_cursor,
        int2* __restrict__ csr_bin) {
    __shared__ int2 sdata[K3_CHUNK];                 // 32 KB
    __shared__ unsigned short sbinid[K3_CHUNK];      // 8 KB
    __shared__ int swhist[4][NBINS];                 // per-wave hist
    __shared__ int swcur[4][NBINS];                  // per-wave scatter cursor
    __shared__ int stot[NBINS];
    __shared__ int lscan[NBINS];
    __shared__ int sbase[NBINS];
    __shared__ int stmp[512];
    int t = threadIdx.x;
    int wv = t >> 6;
    int base_e = blockIdx.x * K3_CHUNK;

    for (int b = t; b < NBINS; b += 256) {
        swhist[0][b] = 0; swhist[1][b] = 0; swhist[2][b] = 0; swhist[3][b] = 0;
    }
    __syncthreads();

    int2 myedge[K3_PER_T];
    short mybin[K3_PER_T];
#pragma unroll
    for (int k = 0; k < K3_PER_T; ++k) {
        int e = base_e + t + k * 256;
        if (e < N_EDGES) {
            int d = min(max(dst[e], 0), N_NODES - 1);
            int s = min(max(src[e], 0), N_NODES - 1);
            int b = d >> PBITS;
            mybin[k] = (short)b;
            myedge[k] = make_int2((s << PBITS) | (d & (PNODES - 1)),
                                  __float_as_int(w[e]));
            atomicAdd(&swhist[wv][b], 1);
        } else mybin[k] = -1;
    }
    __syncthreads();
    // totals + block scan over 512 (2 elems/thread Hillis-Steele)
    for (int i = t; i < 512; i += 256) {
        int v = 0;
        if (i < NBINS)
            v = swhist[0][i] + swhist[1][i] + swhist[2][i] + swhist[3][i];
        if (i < NBINS) stot[i] = v;
        stmp[i] = v;
    }
    __syncthreads();
    for (int off = 1; off < 512; off <<= 1) {
        int i0 = t, i1 = t + 256;
        int v0 = (i0 >= off) ? stmp[i0 - off] : 0;
        int v1 = (i1 >= off) ? stmp[i1 - off] : 0;
        __syncthreads();
        stmp[i0] += v0; stmp[i1] += v1;
        __syncthreads();
    }
    // same thread writes and reads lscan[b] (same b in both loops): no race
    for (int b = t; b < NBINS; b += 256) lscan[b] = stmp[b] - stot[b];
    for (int b = t; b < NBINS; b += 256) {
        int c = stot[b];
        if (c > 0) sbase[b] = atomicAdd(&bin_cursor[b], c);
        int run = lscan[b];
        swcur[0][b] = run; run += swhist[0][b];
        swcur[1][b] = run; run += swhist[1][b];
        swcur[2][b] = run; run += swhist[2][b];
        swcur[3][b] = run;
    }
    __syncthreads();
    // LDS scatter: each wave only contends on its own cursor copy
#pragma unroll
    for (int k = 0; k < K3_PER_T; ++k) {
        int b = mybin[k];
        if (b >= 0) {
            int p = atomicAdd(&swcur[wv][b], 1);
            sdata[p] = myedge[k];
            sbinid[p] = (unsigned short)b;
        }
    }
    __syncthreads();
    int cnt = min(N_EDGES - base_e, K3_CHUNK);
#pragma unroll
    for (int k = 0; k < K3_PER_T; ++k) {
        int p = t + k * 256;
        if (p < cnt) {
            int b = sbinid[p];
            int idx = sbase[b] + (p - lscan[b]);
            idx = min(idx, (b + 1) * BIN_CAP - 1);   // overflow-safe (no fault)
            csr_bin[idx] = sdata[p];
        }
    }
}

// K4: one block per bin — wave-privatized node histogram -> row_range,
// then wave-privatized scatter inside the bin's region.
__global__ __launch_bounds__(256) void bin_csr_kernel(
        const int* __restrict__ bin_cursor, const int2* __restrict__ csr_bin,
        int2* __restrict__ csr_edge, int2* __restrict__ row_range) {
    __shared__ int lwhist[4][PNODES];
    __shared__ int lwcur[4][PNODES];
    __shared__ int ltot[PNODES];
    __shared__ int ltmp[PNODES];
    int b = blockIdx.x;
    int t = threadIdx.x;
    int wv = t >> 6;
    int base = b * BIN_CAP;
    int cnt = min(bin_cursor[b] - base, BIN_CAP);
    if (t < PNODES) {
        lwhist[0][t] = 0; lwhist[1][t] = 0; lwhist[2][t] = 0; lwhist[3][t] = 0;
    }
    __syncthreads();
    {
        int j = t;
        for (; j + 256 < cnt; j += 512) {
            int2 e0 = csr_bin[base + j];
            int2 e1 = csr_bin[base + j + 256];
            atomicAdd(&lwhist[wv][e0.x & (PNODES - 1)], 1);
            atomicAdd(&lwhist[wv][e1.x & (PNODES - 1)], 1);
        }
        if (j < cnt) atomicAdd(&lwhist[wv][csr_bin[base + j].x & (PNODES - 1)], 1);
    }
    __syncthreads();
    if (t < PNODES) {
        int v = lwhist[0][t] + lwhist[1][t] + lwhist[2][t] + lwhist[3][t];
        ltot[t] = v; ltmp[t] = v;
    }
    __syncthreads();
    for (int off = 1; off < PNODES; off <<= 1) {
        int a = 0;
        if (t < PNODES && t >= off) a = ltmp[t - off];
        __syncthreads();
        if (t < PNODES) ltmp[t] += a;
        __syncthreads();
    }
    if (t < PNODES) {
        int beg = base + ltmp[t] - ltot[t];
        int node = b * PNODES + t;
        if (node < N_NODES) row_range[node] = make_int2(beg, beg + ltot[t]);
        int run = beg;
        lwcur[0][t] = run; run += lwhist[0][t];
        lwcur[1][t] = run; run += lwhist[1][t];
        lwcur[2][t] = run; run += lwhist[2][t];
        lwcur[3][t] = run;
    }
    __syncthreads();
    {
        int j = t;
        for (; j + 256 < cnt; j += 512) {
            int2 e0 = csr_bin[base + j];
            int2 e1 = csr_bin[base + j + 256];
            int p0 = atomicAdd(&lwcur[wv][e0.x & (PNODES - 1)], 1);
            int p1 = atomicAdd(&lwcur[wv][e1.x & (PNODES - 1)], 1);
            csr_edge[p0] = make_int2(e0.x >> PBITS, e0.y);
            csr_edge[p1] = make_int2(e1.x >> PBITS, e1.y);
        }
        if (j < cnt) {
            int2 e0 = csr_bin[base + j];
            int p0 = atomicAdd(&lwcur[wv][e0.x & (PNODES - 1)], 1);
            csr_edge[p0] = make_int2(e0.x >> PBITS, e0.y);
        }
    }
}

// ======================= dense GEMM 1 ======================================

#define BK 16
__global__ __launch_bounds__(256) void gemm1_tiled(const float* __restrict__ x,
                                                   const float* __restrict__ W1,
                                                   unsigned short* __restrict__ s1b) {
    __shared__ float xT[BK][68];
    __shared__ float wt[BK][64];
    int t = threadIdx.x;
    int n_base = blockIdx.x * 64;
    int cq = t & 15;
    int nq = t >> 4;
    int ld_node = t >> 2;
    int ld_k4   = (t & 3) * 4;
    int gnode = min(n_base + ld_node, N_NODES - 1);
    const float* xrow = x + (size_t)gnode * NFEAT;
    int wr = t >> 4;
    int wc = (t & 15) * 4;
    float acc[4][4] = {};
    for (int k0 = 0; k0 < NFEAT; k0 += BK) {
        float4 xv = *(const float4*)(xrow + k0 + ld_k4);
        xT[ld_k4 + 0][ld_node] = xv.x;
        xT[ld_k4 + 1][ld_node] = xv.y;
        xT[ld_k4 + 2][ld_node] = xv.z;
        xT[ld_k4 + 3][ld_node] = xv.w;
        *(float4*)&wt[wr][wc] = *(const float4*)(W1 + (size_t)(k0 + wr) * NHID + wc);
        __syncthreads();
#pragma unroll
        for (int k = 0; k < BK; ++k) {
            float4 a = *(const float4*)&xT[k][4 * nq];
            float4 bb = *(const float4*)&wt[k][4 * cq];
            acc[0][0] = fmaf(a.x, bb.x, acc[0][0]);
            acc[0][1] = fmaf(a.x, bb.y, acc[0][1]);
            acc[0][2] = fmaf(a.x, bb.z, acc[0][2]);
            acc[0][3] = fmaf(a.x, bb.w, acc[0][3]);
            acc[1][0] = fmaf(a.y, bb.x, acc[1][0]);
            acc[1][1] = fmaf(a.y, bb.y, acc[1][1]);
            acc[1][2] = fmaf(a.y, bb.z, acc[1][2]);
            acc[1][3] = fmaf(a.y, bb.w, acc[1][3]);
            acc[2][0] = fmaf(a.z, bb.x, acc[2][0]);
            acc[2][1] = fmaf(a.z, bb.y, acc[2][1]);
            acc[2][2] = fmaf(a.z, bb.z, acc[2][2]);
            acc[2][3] = fmaf(a.z, bb.w, acc[2][3]);
            acc[3][0] = fmaf(a.w, bb.x, acc[3][0]);
            acc[3][1] = fmaf(a.w, bb.y, acc[3][1]);
            acc[3][2] = fmaf(a.w, bb.z, acc[3][2]);
            acc[3][3] = fmaf(a.w, bb.w, acc[3][3]);
        }
        __syncthreads();
    }
#pragma unroll
    for (int i = 0; i < 4; ++i) {
        int n = n_base + 4 * nq + i;
        if (n < N_NODES) {
            ushort4 o;
            o.x = f2bf(acc[i][0]); o.y = f2bf(acc[i][1]);
            o.z = f2bf(acc[i][2]); o.w = f2bf(acc[i][3]);
            *(ushort4*)&s1b[(size_t)n * NHID + 4 * cq] = o;
        }
    }
}

// ======================= fused SpMM1 + bias/ReLU + GEMM2 ===================
// R11-exact (fp32 s2 out): 8-edge unrolled gathers.
__global__ __launch_bounds__(256) void spmm1_fused_kernel(
        const int2* __restrict__ row_range,
        const int2* __restrict__ csr_edge,
        const unsigned int* __restrict__ s1p,
        const float* __restrict__ b1,
        const float* __restrict__ W2,
        float* __restrict__ s2) {
    __shared__ float W2s[NHID * NCLASS];   // 4 KB
    __shared__ float hsh[8][NHID];         // 2 KB
    int t = threadIdx.x;
    for (int i = t; i < NHID * NCLASS; i += 256) W2s[i] = W2[i];
    __syncthreads();

    int g = t >> 5, lane = t & 31;
    int node = blockIdx.x * 8 + g;         // 6250 blocks, exact
    int2 rr = row_range[node];
    int beg = rr.x, end = rr.y;
    float2 a0 = {0.f, 0.f}, a1 = {0.f, 0.f}, a2 = {0.f, 0.f}, a3 = {0.f, 0.f};
    int j = beg;
    for (; j + 7 < end; j += 8) {
        int2 e0 = csr_edge[j],     e1 = csr_edge[j + 1];
        int2 e2 = csr_edge[j + 2], e3 = csr_edge[j + 3];
        int2 e4 = csr_edge[j + 4], e5 = csr_edge[j + 5];
        int2 e6 = csr_edge[j + 6], e7 = csr_edge[j + 7];
        unsigned v0 = s1p[(size_t)e0.x * 32 + lane];
        unsigned v1 = s1p[(size_t)e1.x * 32 + lane];
        unsigned v2 = s1p[(size_t)e2.x * 32 + lane];
        unsigned v3 = s1p[(size_t)e3.x * 32 + lane];
        unsigned v4 = s1p[(size_t)e4.x * 32 + lane];
        unsigned v5 = s1p[(size_t)e5.x * 32 + lane];
        unsigned v6 = s1p[(size_t)e6.x * 32 + lane];
        unsigned v7 = s1p[(size_t)e7.x * 32 + lane];
        float w0 = __int_as_float(e0.y), w1 = __int_as_float(e1.y);
        float w2 = __int_as_float(e2.y), w3 = __int_as_float(e3.y);
        float w4 = __int_as_float(e4.y), w5 = __int_as_float(e5.y);
        float w6 = __int_as_float(e6.y), w7 = __int_as_float(e7.y);
        a0.x = fmaf(w0, __uint_as_float(v0 << 16), a0.x);
        a0.y = fmaf(w0, __uint_as_float(v0 & 0xFFFF0000u), a0.y);
        a1.x = fmaf(w1, __uint_as_float(v1 << 16), a1.x);
        a1.y = fmaf(w1, __uint_as_float(v1 & 0xFFFF0000u), a1.y);
        a2.x = fmaf(w2, __uint_as_float(v2 << 16), a2.x);
        a2.y = fmaf(w2, __uint_as_float(v2 & 0xFFFF0000u), a2.y);
        a3.x = fmaf(w3, __uint_as_float(v3 << 16), a3.x);
        a3.y = fmaf(w3, __uint_as_float(v3 & 0xFFFF0000u), a3.y);
        a0.x = fmaf(w4, __uint_as_float(v4 << 16), a0.x);
        a0.y = fmaf(w4, __uint_as_float(v4 & 0xFFFF0000u), a0.y);
        a1.x = fmaf(w5, __uint_as_float(v5 << 16), a1.x);
        a1.y = fmaf(w5, __uint_as_float(v5 & 0xFFFF0000u), a1.y);
        a2.x = fmaf(w6, __uint_as_float(v6 << 16), a2.x);
        a2.y = fmaf(w6, __uint_as_float(v6 & 0xFFFF0000u), a2.y);
        a3.x = fmaf(w7, __uint_as_float(v7 << 16), a3.x);
        a3.y = fmaf(w7, __uint_as_float(v7 & 0xFFFF0000u), a3.y);
    }
    for (; j + 3 < end; j += 4) {
        int2 e0 = csr_edge[j],     e1 = csr_edge[j + 1];
        int2 e2 = csr_edge[j + 2], e3 = csr_edge[j + 3];
        unsigned v0 = s1p[(size_t)e0.x * 32 + lane];
        unsigned v1 = s1p[(size_t)e1.x * 32 + lane];
        unsigned v2 = s1p[(size_t)e2.x * 32 + lane];
        unsigned v3 = s1p[(size_t)e3.x * 32 + lane];
        float w0 = __int_as_float(e0.y), w1 = __int_as_float(e1.y);
        float w2 = __int_as_float(e2.y), w3 = __int_as_float(e3.y);
        a0.x = fmaf(w0, __uint_as_float(v0 << 16), a0.x);
        a0.y = fmaf(w0, __uint_as_float(v0 & 0xFFFF0000u), a0.y);
        a1.x = fmaf(w1, __uint_as_float(v1 << 16), a1.x);
        a1.y = fmaf(w1, __uint_as_float(v1 & 0xFFFF0000u), a1.y);
        a2.x = fmaf(w2, __uint_as_float(v2 << 16), a2.x);
        a2.y = fmaf(w2, __uint_as_float(v2 & 0xFFFF0000u), a2.y);
        a3.x = fmaf(w3, __uint_as_float(v3 << 16), a3.x);
        a3.y = fmaf(w3, __uint_as_float(v3 & 0xFFFF0000u), a3.y);
    }
    for (; j < end; ++j) {
        int2 e0 = csr_edge[j];
        unsigned v0 = s1p[(size_t)e0.x * 32 + lane];
        float w0 = __int_as_float(e0.y);
        a0.x = fmaf(w0, __uint_as_float(v0 << 16), a0.x);
        a0.y = fmaf(w0, __uint_as_float(v0 & 0xFFFF0000u), a0.y);
    }
    float2 bb = *(const float2*)&b1[2 * lane];
    float vx = (a0.x + a1.x) + (a2.x + a3.x) + bb.x;
    float vy = (a0.y + a1.y) + (a2.y + a3.y) + bb.y;
    *(float2*)&hsh[g][2 * lane] =
        make_float2(vx > 0.f ? vx : 0.f, vy > 0.f ? vy : 0.f);
    if (lane < NCLASS) {
        float acc = 0.f;
#pragma unroll 16
        for (int k = 0; k < NHID; ++k)
            acc = fmaf(hsh[g][k], W2s[k * NCLASS + lane], acc);
        s2[(size_t)node * NCLASS + lane] = acc;
    }
}

// ======================= SpMM2 + bias + log_softmax ========================
// R11-exact: fp32 s2, 16 lanes/node, 8-edge unrolled.
__global__ void spmm2_csr_kernel(const int2* __restrict__ row_range,
                                 const int2* __restrict__ csr_edge,
                                 const float* __restrict__ s2,
                                 const float* __restrict__ b2,
                                 float* __restrict__ out) {
    int node = blockIdx.x * 16 + (threadIdx.x >> 4);
    if (node >= N_NODES) return;
    int c = threadIdx.x & 15;
    int2 rr = row_range[node];
    int beg = rr.x, end = rr.y;
    float acc0 = 0.f, acc1 = 0.f, acc2 = 0.f, acc3 = 0.f;
    int j = beg;
    for (; j + 7 < end; j += 8) {
        int2 e0 = csr_edge[j],     e1 = csr_edge[j + 1];
        int2 e2 = csr_edge[j + 2], e3 = csr_edge[j + 3];
        int2 e4 = csr_edge[j + 4], e5 = csr_edge[j + 5];
        int2 e6 = csr_edge[j + 6], e7 = csr_edge[j + 7];
        float g0 = s2[(size_t)e0.x * NCLASS + c];
        float g1 = s2[(size_t)e1.x * NCLASS + c];
        float g2 = s2[(size_t)e2.x * NCLASS + c];
        float g3 = s2[(size_t)e3.x * NCLASS + c];
        float g4 = s2[(size_t)e4.x * NCLASS + c];
        float g5 = s2[(size_t)e5.x * NCLASS + c];
        float g6 = s2[(size_t)e6.x * NCLASS + c];
        float g7 = s2[(size_t)e7.x * NCLASS + c];
        acc0 = fmaf(__int_as_float(e0.y), g0, acc0);
        acc1 = fmaf(__int_as_float(e1.y), g1, acc1);
        acc2 = fmaf(__int_as_float(e2.y), g2, acc2);
        acc3 = fmaf(__int_as_float(e3.y), g3, acc3);
        acc0 = fmaf(__int_as_float(e4.y), g4, acc0);
        acc1 = fmaf(__int_as_float(e5.y), g5, acc1);
        acc2 = fmaf(__int_as_float(e6.y), g6, acc2);
        acc3 = fmaf(__int_as_float(e7.y), g7, acc3);
    }
    for (; j + 3 < end; j += 4) {
        int2 e0 = csr_edge[j],     e1 = csr_edge[j + 1];
        int2 e2 = csr_edge[j + 2], e3 = csr_edge[j + 3];
        acc0 = fmaf(__int_as_float(e0.y), s2[(size_t)e0.x * NCLASS + c], acc0);
        acc1 = fmaf(__int_as_float(e1.y), s2[(size_t)e1.x * NCLASS + c], acc1);
        acc2 = fmaf(__int_as_float(e2.y), s2[(size_t)e2.x * NCLASS + c], acc2);
        acc3 = fmaf(__int_as_float(e3.y), s2[(size_t)e3.x * NCLASS + c], acc3);
    }
    for (; j < end; ++j) {
        int2 e0 = csr_edge[j];
        acc0 = fmaf(__int_as_float(e0.y), s2[(size_t)e0.x * NCLASS + c], acc0);
    }
    float v = (acc0 + acc1) + (acc2 + acc3) + b2[c];
    float mx = v;
    for (int off = 8; off; off >>= 1) mx = fmaxf(mx, __shfl_xor(mx, off, 16));
    float ss = expf(v - mx);
    for (int off = 8; off; off >>= 1) ss += __shfl_xor(ss, off, 16);
    out[(size_t)node * NCLASS + c] = v - mx - logf(ss);
}

// ======================= fallback path (R3 atomic version) =================

__global__ void zero_kernel(float* __restrict__ h, float* __restrict__ out) {
    int i = blockIdx.x * 256 + threadIdx.x;
    if (i < N_NODES * NHID) h[i] = 0.f;
    if (i < N_NODES * NCLASS) out[i] = 0.f;
}

__global__ void gemm1_kernel(const float* __restrict__ x,
                             const float* __restrict__ W1,
                             float* __restrict__ s1) {
    int node = blockIdx.x * 4 + (threadIdx.x >> 6);
    int col  = threadIdx.x & 63;
    if (node >= N_NODES) return;
    const float* xr = x + (size_t)node * NFEAT;
    float sum = 0.f;
#pragma unroll 8
    for (int k = 0; k < NFEAT; ++k)
        sum = fmaf(xr[k], W1[k * NHID + col], sum);
    s1[(size_t)node * NHID + col] = sum;
}

__global__ void spmm1_kernel(const int* __restrict__ src, const int* __restrict__ dst,
                             const float* __restrict__ w, const float* __restrict__ s1,
                             float* __restrict__ h) {
    int e = blockIdx.x * 4 + (threadIdx.x >> 6);
    if (e >= N_EDGES) return;
    int lane = threadIdx.x & 63;
    int s = min(max(src[e], 0), N_NODES - 1);
    int d = min(max(dst[e], 0), N_NODES - 1);
    float v = w[e] * s1[(size_t)s * NHID + lane];
    atomicAdd(&h[(size_t)d * NHID + lane], v);
}

__global__ void bias_relu_kernel(float* __restrict__ h, const float* __restrict__ b1) {
    int i = blockIdx.x * 256 + threadIdx.x;
    if (i >= N_NODES * NHID) return;
    float v = h[i] + b1[i & (NHID - 1)];
    h[i] = v > 0.f ? v : 0.f;
}

__global__ void gemm2_kernel(const float* __restrict__ h,
                             const float* __restrict__ W2,
                             float* __restrict__ s2) {
    int node = blockIdx.x * 16 + (threadIdx.x >> 4);
    int col  = threadIdx.x & 15;
    if (node >= N_NODES) return;
    const float* hr = h + (size_t)node * NHID;
    float sum = 0.f;
#pragma unroll 8
    for (int k = 0; k < NHID; ++k)
        sum = fmaf(hr[k], W2[k * NCLASS + col], sum);
    s2[(size_t)node * NCLASS + col] = sum;
}

__global__ void spmm2_kernel(const int* __restrict__ src, const int* __restrict__ dst,
                             const float* __restrict__ w, const float* __restrict__ s2,
                             float* __restrict__ out) {
    int e = blockIdx.x * 16 + (threadIdx.x >> 4);
    if (e >= N_EDGES) return;
    int lane = threadIdx.x & 15;
    int s = min(max(src[e], 0), N_NODES - 1);
    int d = min(max(dst[e], 0), N_NODES - 1);
    float v = w[e] * s2[(size_t)s * NCLASS + lane];
    atomicAdd(&out[(size_t)d * NCLASS + lane], v);
}

__global__ void logsoftmax_kernel(float* __restrict__ out, const float* __restrict__ b2) {
    int n = blockIdx.x * 256 + threadIdx.x;
    if (n >= N_NODES) return;
    float v[NCLASS];
    float mx = -INFINITY;
#pragma unroll
    for (int c = 0; c < NCLASS; ++c) {
        v[c] = out[(size_t)n * NCLASS + c] + b2[c];
        mx = fmaxf(mx, v[c]);
    }
    float ssum = 0.f;
#pragma unroll
    for (int c = 0; c < NCLASS; ++c) ssum += expf(v[c] - mx);
    float ls = mx + logf(ssum);
#pragma unroll
    for (int c = 0; c < NCLASS; ++c) out[(size_t)n * NCLASS + c] = v[c] - ls;
}

// ======================= launch ============================================

extern "C" void kernel_launch(void* const* d_in, const int* in_sizes, int n_in,
                              void* d_out, int out_size, void* d_ws, size_t ws_size,
                              hipStream_t stream) {
    if (n_in != 8) return;
    const int expected[8] = { N_NODES * NFEAT, NFEAT * NHID, NHID,
                              NHID * NCLASS, NCLASS, N_EDGES, N_EDGES, N_EDGES };
    for (int i = 0; i < 8; ++i)
        if (in_sizes[i] != expected[i]) return;
    if (out_size != N_NODES * NCLASS) return;

    const float* x  = (const float*)d_in[0];
    const float* W1 = (const float*)d_in[1];
    const float* b1 = (const float*)d_in[2];
    const float* W2 = (const float*)d_in[3];
    const float* b2 = (const float*)d_in[4];
    const int* edge_src = (const int*)d_in[5];
    const int* edge_dst = (const int*)d_in[6];
    const float* edge_w = (const float*)d_in[7];
    float* out = (float*)d_out;

    const size_t S1_ELTS = (size_t)N_NODES * NHID;          // 3.2M
    const size_t CAP_WORDS = (size_t)NBINS * BIN_CAP * 2;   // int2 region, words
    const size_t NEW_WORDS = 2 * CAP_WORDS + 2 * (size_t)N_NODES + NBINS + 64;
    if (ws_size >= NEW_WORDS * 4) {
        int2*  csr_bin   = (int2*)d_ws;                      // slot A (16 MB)
        unsigned short* s1b = (unsigned short*)d_ws;          // aliases A[0,6.4MB)
        float* s2        = (float*)d_ws + S1_ELTS / 2;        // aliases A[6.4,9.6MB)
        int2*  csr_edge  = (int2*)((int*)d_ws + CAP_WORDS);
        int2*  row_range = (int2*)((int*)csr_edge + CAP_WORDS);
        int*   bin_cursor = (int*)row_range + 2 * N_NODES;

        // --- CSR build ---
        init_cursor_kernel<<<(NBINS + 255) / 256, 256, 0, stream>>>(bin_cursor);
        bin_scatter_kernel<<<K3_BLOCKS, 256, 0, stream>>>(
            edge_src, edge_dst, edge_w, bin_cursor, csr_bin);
        bin_csr_kernel<<<NBINS, 256, 0, stream>>>(
            bin_cursor, csr_bin, csr_edge, row_range);

        // --- layer 1 + fused layer-2 GEMM ---
        gemm1_tiled<<<(N_NODES + 63) / 64, 256, 0, stream>>>(x, W1, s1b);
        spmm1_fused_kernel<<<N_NODES / 8, 256, 0, stream>>>(
            row_range, csr_edge, (const unsigned int*)s1b, b1, W2, s2);
        // --- layer 2 aggregation + epilogue ---
        spmm2_csr_kernel<<<(N_NODES + 15) / 16, 256, 0, stream>>>(
            row_range, csr_edge, s2, b2, out);
        return;
    }

    // --- fallback: proven atomic path (25.6 MB ws) ---
    if (ws_size < 2 * S1_ELTS * sizeof(float)) return;
    float* s1 = (float*)d_ws;
    float* h  = s1 + S1_ELTS;
    float* s2 = s1;
    zero_kernel<<<(N_NODES * NHID + 255) / 256, 256, 0, stream>>>(h, out);
    gemm1_kernel<<<(N_NODES + 3) / 4, 256, 0, stream>>>(x, W1, s1);
    spmm1_kernel<<<(N_EDGES + 3) / 4, 256, 0, stream>>>(edge_src, edge_dst, edge_w, s1, h);
    bias_relu_kernel<<<(N_NODES * NHID + 255) / 256, 256, 0, stream>>>(h, b1);
    gemm2_kernel<<<(N_NODES + 15) / 16, 256, 0, stream>>>(h, W2, s2);
    spmm2_kernel<<<(N_EDGES + 15) / 16, 256, 0, stream>>>(edge_src, edge_dst, edge_w, s2, out);
    logsoftmax_kernel<<<(N_NODES + 255) / 256, 256, 0, stream>>>(out, b2);
}

// Round 14
// 215.692 us; speedup vs baseline: 1.0208x; 1.0208x over previous
//
#include <hip/hip_runtime.h>
#include <math.h>

#define N_NODES 50000
#define N_EDGES 1600000
#define NFEAT 256
#define NHID 64
#define NCLASS 16

#define PBITS 7
#define PNODES 128                       // nodes per bin
#define NBINS ((N_NODES + PNODES - 1) / PNODES)   // 391
#define BIN_CAP 5120                     // mean 4092, sigma 64 -> +16 sigma
#define K3_CHUNK 4096
#define K3_PER_T 16                      // 4096 / 256
#define K3_BLOCKS ((N_EDGES + K3_CHUNK - 1) / K3_CHUNK)  // 391

__device__ inline unsigned short f2bf(float f) {     // RNE f32 -> bf16
    unsigned u = __float_as_uint(f);
    return (unsigned short)((u + 0x7FFFu + ((u >> 16) & 1u)) >> 16);
}

// ======================= counting-sort CSR build ===========================

__global__ void init_cursor_kernel(int* __restrict__ bin_cursor) {
    int b = blockIdx.x * 256 + threadIdx.x;
    if (b < NBINS) bin_cursor[b] = b * BIN_CAP;
}

// K3: per-block local counting sort by bin -> bin-grouped csr_bin.
// (R13-proven wave-privatized version, unchanged.)
__global__ __launch_bounds__(256) void bin_scatter_kernel(
        const int* __restrict__ src, const int* __restrict__ dst,
        const float* __restrict__ w, int* __restrict__ bin_cursor,
        int2* __restrict__ csr_bin) {
    __shared__ int2 sdata[K3_CHUNK];                 // 32 KB
    __shared__ unsigned short sbinid[K3_CHUNK];      // 8 KB
    __shared__ int swhist[4][NBINS];
    __shared__ int swcur[4][NBINS];
    __shared__ int stot[NBINS];
    __shared__ int lscan[NBINS];
    __shared__ int sbase[NBINS];
    __shared__ int stmp[512];
    int t = threadIdx.x;
    int wv = t >> 6;
    int base_e = blockIdx.x * K3_CHUNK;

    for (int b = t; b < NBINS; b += 256) {
        swhist[0][b] = 0; swhist[1][b] = 0; swhist[2][b] = 0; swhist[3][b] = 0;
    }
    __syncthreads();

    int2 myedge[K3_PER_T];
    short mybin[K3_PER_T];
#pragma unroll
    for (int k = 0; k < K3_PER_T; ++k) {
        int e = base_e + t + k * 256;
        if (e < N_EDGES) {
            int d = min(max(dst[e], 0), N_NODES - 1);
            int s = min(max(src[e], 0), N_NODES - 1);
            int b = d >> PBITS;
            mybin[k] = (short)b;
            myedge[k] = make_int2((s << PBITS) | (d & (PNODES - 1)),
                                  __float_as_int(w[e]));
            atomicAdd(&swhist[wv][b], 1);
        } else mybin[k] = -1;
    }
    __syncthreads();
    for (int i = t; i < 512; i += 256) {
        int v = 0;
        if (i < NBINS)
            v = swhist[0][i] + swhist[1][i] + swhist[2][i] + swhist[3][i];
        if (i < NBINS) stot[i] = v;
        stmp[i] = v;
    }
    __syncthreads();
    for (int off = 1; off < 512; off <<= 1) {
        int i0 = t, i1 = t + 256;
        int v0 = (i0 >= off) ? stmp[i0 - off] : 0;
        int v1 = (i1 >= off) ? stmp[i1 - off] : 0;
        __syncthreads();
        stmp[i0] += v0; stmp[i1] += v1;
        __syncthreads();
    }
    for (int b = t; b < NBINS; b += 256) lscan[b] = stmp[b] - stot[b];
    for (int b = t; b < NBINS; b += 256) {
        int c = stot[b];
        if (c > 0) sbase[b] = atomicAdd(&bin_cursor[b], c);
        int run = lscan[b];
        swcur[0][b] = run; run += swhist[0][b];
        swcur[1][b] = run; run += swhist[1][b];
        swcur[2][b] = run; run += swhist[2][b];
        swcur[3][b] = run;
    }
    __syncthreads();
#pragma unroll
    for (int k = 0; k < K3_PER_T; ++k) {
        int b = mybin[k];
        if (b >= 0) {
            int p = atomicAdd(&swcur[wv][b], 1);
            sdata[p] = myedge[k];
            sbinid[p] = (unsigned short)b;
        }
    }
    __syncthreads();
    int cnt = min(N_EDGES - base_e, K3_CHUNK);
#pragma unroll
    for (int k = 0; k < K3_PER_T; ++k) {
        int p = t + k * 256;
        if (p < cnt) {
            int b = sbinid[p];
            int idx = sbase[b] + (p - lscan[b]);
            idx = min(idx, (b + 1) * BIN_CAP - 1);   // overflow-safe (no fault)
            csr_bin[idx] = sdata[p];
        }
    }
}

// K4: (R13-proven wave-privatized version, unchanged.)
__global__ __launch_bounds__(256) void bin_csr_kernel(
        const int* __restrict__ bin_cursor, const int2* __restrict__ csr_bin,
        int2* __restrict__ csr_edge, int2* __restrict__ row_range) {
    __shared__ int lwhist[4][PNODES];
    __shared__ int lwcur[4][PNODES];
    __shared__ int ltot[PNODES];
    __shared__ int ltmp[PNODES];
    int b = blockIdx.x;
    int t = threadIdx.x;
    int wv = t >> 6;
    int base = b * BIN_CAP;
    int cnt = min(bin_cursor[b] - base, BIN_CAP);
    if (t < PNODES) {
        lwhist[0][t] = 0; lwhist[1][t] = 0; lwhist[2][t] = 0; lwhist[3][t] = 0;
    }
    __syncthreads();
    {
        int j = t;
        for (; j + 256 < cnt; j += 512) {
            int2 e0 = csr_bin[base + j];
            int2 e1 = csr_bin[base + j + 256];
            atomicAdd(&lwhist[wv][e0.x & (PNODES - 1)], 1);
            atomicAdd(&lwhist[wv][e1.x & (PNODES - 1)], 1);
        }
        if (j < cnt) atomicAdd(&lwhist[wv][csr_bin[base + j].x & (PNODES - 1)], 1);
    }
    __syncthreads();
    if (t < PNODES) {
        int v = lwhist[0][t] + lwhist[1][t] + lwhist[2][t] + lwhist[3][t];
        ltot[t] = v; ltmp[t] = v;
    }
    __syncthreads();
    for (int off = 1; off < PNODES; off <<= 1) {
        int a = 0;
        if (t < PNODES && t >= off) a = ltmp[t - off];
        __syncthreads();
        if (t < PNODES) ltmp[t] += a;
        __syncthreads();
    }
    if (t < PNODES) {
        int beg = base + ltmp[t] - ltot[t];
        int node = b * PNODES + t;
        if (node < N_NODES) row_range[node] = make_int2(beg, beg + ltot[t]);
        int run = beg;
        lwcur[0][t] = run; run += lwhist[0][t];
        lwcur[1][t] = run; run += lwhist[1][t];
        lwcur[2][t] = run; run += lwhist[2][t];
        lwcur[3][t] = run;
    }
    __syncthreads();
    {
        int j = t;
        for (; j + 256 < cnt; j += 512) {
            int2 e0 = csr_bin[base + j];
            int2 e1 = csr_bin[base + j + 256];
            int p0 = atomicAdd(&lwcur[wv][e0.x & (PNODES - 1)], 1);
            int p1 = atomicAdd(&lwcur[wv][e1.x & (PNODES - 1)], 1);
            csr_edge[p0] = make_int2(e0.x >> PBITS, e0.y);
            csr_edge[p1] = make_int2(e1.x >> PBITS, e1.y);
        }
        if (j < cnt) {
            int2 e0 = csr_bin[base + j];
            int p0 = atomicAdd(&lwcur[wv][e0.x & (PNODES - 1)], 1);
            csr_edge[p0] = make_int2(e0.x >> PBITS, e0.y);
        }
    }
}

// ======================= dense GEMM 1 ======================================

#define BK 16
__global__ __launch_bounds__(256) void gemm1_tiled(const float* __restrict__ x,
                                                   const float* __restrict__ W1,
                                                   unsigned short* __restrict__ s1b) {
    __shared__ float xT[BK][68];
    __shared__ float wt[BK][64];
    int t = threadIdx.x;
    int n_base = blockIdx.x * 64;
    int cq = t & 15;
    int nq = t >> 4;
    int ld_node = t >> 2;
    int ld_k4   = (t & 3) * 4;
    int gnode = min(n_base + ld_node, N_NODES - 1);
    const float* xrow = x + (size_t)gnode * NFEAT;
    int wr = t >> 4;
    int wc = (t & 15) * 4;
    float acc[4][4] = {};
    for (int k0 = 0; k0 < NFEAT; k0 += BK) {
        float4 xv = *(const float4*)(xrow + k0 + ld_k4);
        xT[ld_k4 + 0][ld_node] = xv.x;
        xT[ld_k4 + 1][ld_node] = xv.y;
        xT[ld_k4 + 2][ld_node] = xv.z;
        xT[ld_k4 + 3][ld_node] = xv.w;
        *(float4*)&wt[wr][wc] = *(const float4*)(W1 + (size_t)(k0 + wr) * NHID + wc);
        __syncthreads();
#pragma unroll
        for (int k = 0; k < BK; ++k) {
            float4 a = *(const float4*)&xT[k][4 * nq];
            float4 bb = *(const float4*)&wt[k][4 * cq];
            acc[0][0] = fmaf(a.x, bb.x, acc[0][0]);
            acc[0][1] = fmaf(a.x, bb.y, acc[0][1]);
            acc[0][2] = fmaf(a.x, bb.z, acc[0][2]);
            acc[0][3] = fmaf(a.x, bb.w, acc[0][3]);
            acc[1][0] = fmaf(a.y, bb.x, acc[1][0]);
            acc[1][1] = fmaf(a.y, bb.y, acc[1][1]);
            acc[1][2] = fmaf(a.y, bb.z, acc[1][2]);
            acc[1][3] = fmaf(a.y, bb.w, acc[1][3]);
            acc[2][0] = fmaf(a.z, bb.x, acc[2][0]);
            acc[2][1] = fmaf(a.z, bb.y, acc[2][1]);
            acc[2][2] = fmaf(a.z, bb.z, acc[2][2]);
            acc[2][3] = fmaf(a.z, bb.w, acc[2][3]);
            acc[3][0] = fmaf(a.w, bb.x, acc[3][0]);
            acc[3][1] = fmaf(a.w, bb.y, acc[3][1]);
            acc[3][2] = fmaf(a.w, bb.z, acc[3][2]);
            acc[3][3] = fmaf(a.w, bb.w, acc[3][3]);
        }
        __syncthreads();
    }
#pragma unroll
    for (int i = 0; i < 4; ++i) {
        int n = n_base + 4 * nq + i;
        if (n < N_NODES) {
            ushort4 o;
            o.x = f2bf(acc[i][0]); o.y = f2bf(acc[i][1]);
            o.z = f2bf(acc[i][2]); o.w = f2bf(acc[i][3]);
            *(ushort4*)&s1b[(size_t)n * NHID + 4 * cq] = o;
        }
    }
}

// ======================= fused SpMM1 + bias/ReLU + GEMM2 ===================
// v2: 16 lanes/node, uint2 gathers (4 bf16 cols/lane) — halves wave count
// and issued instructions per edge vs 32-lane/uint; 8-edge unroll keeps
// 32 outstanding loads per wave. fp32 s2 out (R13 semantics).
__global__ __launch_bounds__(256) void spmm1_fused_kernel(
        const int2* __restrict__ row_range,
        const int2* __restrict__ csr_edge,
        const uint2* __restrict__ s1p2,
        const float* __restrict__ b1,
        const float* __restrict__ W2,
        float* __restrict__ s2) {
    __shared__ float W2s[NHID * NCLASS];   // 4 KB
    __shared__ float hsh[16][NHID];        // 4 KB
    int t = threadIdx.x;
    for (int i = t; i < NHID * NCLASS; i += 256) W2s[i] = W2[i];
    __syncthreads();

    int g = t >> 4, lane = t & 15;         // 16 groups x 16 lanes
    int node = blockIdx.x * 16 + g;        // 3125 blocks, exact
    int2 rr = row_range[node];
    int beg = rr.x, end = rr.y;
    // acc[k] = col 4*lane+k ; two sets (even/odd edges) for FMA-chain ILP
    float4 accA = {0.f, 0.f, 0.f, 0.f}, accB = {0.f, 0.f, 0.f, 0.f};
    int j = beg;
    for (; j + 7 < end; j += 8) {
        int2 e0 = csr_edge[j],     e1 = csr_edge[j + 1];
        int2 e2 = csr_edge[j + 2], e3 = csr_edge[j + 3];
        int2 e4 = csr_edge[j + 4], e5 = csr_edge[j + 5];
        int2 e6 = csr_edge[j + 6], e7 = csr_edge[j + 7];
        uint2 v0 = s1p2[(size_t)e0.x * 16 + lane];
        uint2 v1 = s1p2[(size_t)e1.x * 16 + lane];
        uint2 v2 = s1p2[(size_t)e2.x * 16 + lane];
        uint2 v3 = s1p2[(size_t)e3.x * 16 + lane];
        uint2 v4 = s1p2[(size_t)e4.x * 16 + lane];
        uint2 v5 = s1p2[(size_t)e5.x * 16 + lane];
        uint2 v6 = s1p2[(size_t)e6.x * 16 + lane];
        uint2 v7 = s1p2[(size_t)e7.x * 16 + lane];
        float w0 = __int_as_float(e0.y), w1 = __int_as_float(e1.y);
        float w2 = __int_as_float(e2.y), w3 = __int_as_float(e3.y);
        float w4 = __int_as_float(e4.y), w5 = __int_as_float(e5.y);
        float w6 = __int_as_float(e6.y), w7 = __int_as_float(e7.y);
        accA.x = fmaf(w0, __uint_as_float(v0.x << 16), accA.x);
        accA.y = fmaf(w0, __uint_as_float(v0.x & 0xFFFF0000u), accA.y);
        accA.z = fmaf(w0, __uint_as_float(v0.y << 16), accA.z);
        accA.w = fmaf(w0, __uint_as_float(v0.y & 0xFFFF0000u), accA.w);
        accB.x = fmaf(w1, __uint_as_float(v1.x << 16), accB.x);
        accB.y = fmaf(w1, __uint_as_float(v1.x & 0xFFFF0000u), accB.y);
        accB.z = fmaf(w1, __uint_as_float(v1.y << 16), accB.z);
        accB.w = fmaf(w1, __uint_as_float(v1.y & 0xFFFF0000u), accB.w);
        accA.x = fmaf(w2, __uint_as_float(v2.x << 16), accA.x);
        accA.y = fmaf(w2, __uint_as_float(v2.x & 0xFFFF0000u), accA.y);
        accA.z = fmaf(w2, __uint_as_float(v2.y << 16), accA.z);
        accA.w = fmaf(w2, __uint_as_float(v2.y & 0xFFFF0000u), accA.w);
        accB.x = fmaf(w3, __uint_as_float(v3.x << 16), accB.x);
        accB.y = fmaf(w3, __uint_as_float(v3.x & 0xFFFF0000u), accB.y);
        accB.z = fmaf(w3, __uint_as_float(v3.y << 16), accB.z);
        accB.w = fmaf(w3, __uint_as_float(v3.y & 0xFFFF0000u), accB.w);
        accA.x = fmaf(w4, __uint_as_float(v4.x << 16), accA.x);
        accA.y = fmaf(w4, __uint_as_float(v4.x & 0xFFFF0000u), accA.y);
        accA.z = fmaf(w4, __uint_as_float(v4.y << 16), accA.z);
        accA.w = fmaf(w4, __uint_as_float(v4.y & 0xFFFF0000u), accA.w);
        accB.x = fmaf(w5, __uint_as_float(v5.x << 16), accB.x);
        accB.y = fmaf(w5, __uint_as_float(v5.x & 0xFFFF0000u), accB.y);
        accB.z = fmaf(w5, __uint_as_float(v5.y << 16), accB.z);
        accB.w = fmaf(w5, __uint_as_float(v5.y & 0xFFFF0000u), accB.w);
        accA.x = fmaf(w6, __uint_as_float(v6.x << 16), accA.x);
        accA.y = fmaf(w6, __uint_as_float(v6.x & 0xFFFF0000u), accA.y);
        accA.z = fmaf(w6, __uint_as_float(v6.y << 16), accA.z);
        accA.w = fmaf(w6, __uint_as_float(v6.y & 0xFFFF0000u), accA.w);
        accB.x = fmaf(w7, __uint_as_float(v7.x << 16), accB.x);
        accB.y = fmaf(w7, __uint_as_float(v7.x & 0xFFFF0000u), accB.y);
        accB.z = fmaf(w7, __uint_as_float(v7.y << 16), accB.z);
        accB.w = fmaf(w7, __uint_as_float(v7.y & 0xFFFF0000u), accB.w);
    }
    for (; j < end; ++j) {
        int2 e0 = csr_edge[j];
        uint2 v0 = s1p2[(size_t)e0.x * 16 + lane];
        float w0 = __int_as_float(e0.y);
        accA.x = fmaf(w0, __uint_as_float(v0.x << 16), accA.x);
        accA.y = fmaf(w0, __uint_as_float(v0.x & 0xFFFF0000u), accA.y);
        accA.z = fmaf(w0, __uint_as_float(v0.y << 16), accA.z);
        accA.w = fmaf(w0, __uint_as_float(v0.y & 0xFFFF0000u), accA.w);
    }
    float4 bb = *(const float4*)&b1[4 * lane];
    float4 hv;
    hv.x = accA.x + accB.x + bb.x;
    hv.y = accA.y + accB.y + bb.y;
    hv.z = accA.z + accB.z + bb.z;
    hv.w = accA.w + accB.w + bb.w;
    hv.x = hv.x > 0.f ? hv.x : 0.f;
    hv.y = hv.y > 0.f ? hv.y : 0.f;
    hv.z = hv.z > 0.f ? hv.z : 0.f;
    hv.w = hv.w > 0.f ? hv.w : 0.f;
    // same-wave LDS park (lockstep, no barrier needed within the wave)
    *(float4*)&hsh[g][4 * lane] = hv;
    // gemm2: all 16 lanes active, one class each
    float acc = 0.f;
#pragma unroll 16
    for (int k = 0; k < NHID; ++k)
        acc = fmaf(hsh[g][k], W2s[k * NCLASS + lane], acc);
    s2[(size_t)node * NCLASS + lane] = acc;
}

// ======================= SpMM2 + bias + log_softmax ========================
// R13-exact: fp32 s2, 16 lanes/node, 8-edge unrolled.
__global__ void spmm2_csr_kernel(const int2* __restrict__ row_range,
                                 const int2* __restrict__ csr_edge,
                                 const float* __restrict__ s2,
                                 const float* __restrict__ b2,
                                 float* __restrict__ out) {
    int node = blockIdx.x * 16 + (threadIdx.x >> 4);
    if (node >= N_NODES) return;
    int c = threadIdx.x & 15;
    int2 rr = row_range[node];
    int beg = rr.x, end = rr.y;
    float acc0 = 0.f, acc1 = 0.f, acc2 = 0.f, acc3 = 0.f;
    int j = beg;
    for (; j + 7 < end; j += 8) {
        int2 e0 = csr_edge[j],     e1 = csr_edge[j + 1];
        int2 e2 = csr_edge[j + 2], e3 = csr_edge[j + 3];
        int2 e4 = csr_edge[j + 4], e5 = csr_edge[j + 5];
        int2 e6 = csr_edge[j + 6], e7 = csr_edge[j + 7];
        float g0 = s2[(size_t)e0.x * NCLASS + c];
        float g1 = s2[(size_t)e1.x * NCLASS + c];
        float g2 = s2[(size_t)e2.x * NCLASS + c];
        float g3 = s2[(size_t)e3.x * NCLASS + c];
        float g4 = s2[(size_t)e4.x * NCLASS + c];
        float g5 = s2[(size_t)e5.x * NCLASS + c];
        float g6 = s2[(size_t)e6.x * NCLASS + c];
        float g7 = s2[(size_t)e7.x * NCLASS + c];
        acc0 = fmaf(__int_as_float(e0.y), g0, acc0);
        acc1 = fmaf(__int_as_float(e1.y), g1, acc1);
        acc2 = fmaf(__int_as_float(e2.y), g2, acc2);
        acc3 = fmaf(__int_as_float(e3.y), g3, acc3);
        acc0 = fmaf(__int_as_float(e4.y), g4, acc0);
        acc1 = fmaf(__int_as_float(e5.y), g5, acc1);
        acc2 = fmaf(__int_as_float(e6.y), g6, acc2);
        acc3 = fmaf(__int_as_float(e7.y), g7, acc3);
    }
    for (; j + 3 < end; j += 4) {
        int2 e0 = csr_edge[j],     e1 = csr_edge[j + 1];
        int2 e2 = csr_edge[j + 2], e3 = csr_edge[j + 3];
        acc0 = fmaf(__int_as_float(e0.y), s2[(size_t)e0.x * NCLASS + c], acc0);
        acc1 = fmaf(__int_as_float(e1.y), s2[(size_t)e1.x * NCLASS + c], acc1);
        acc2 = fmaf(__int_as_float(e2.y), s2[(size_t)e2.x * NCLASS + c], acc2);
        acc3 = fmaf(__int_as_float(e3.y), s2[(size_t)e3.x * NCLASS + c], acc3);
    }
    for (; j < end; ++j) {
        int2 e0 = csr_edge[j];
        acc0 = fmaf(__int_as_float(e0.y), s2[(size_t)e0.x * NCLASS + c], acc0);
    }
    float v = (acc0 + acc1) + (acc2 + acc3) + b2[c];
    float mx = v;
    for (int off = 8; off; off >>= 1) mx = fmaxf(mx, __shfl_xor(mx, off, 16));
    float ss = expf(v - mx);
    for (int off = 8; off; off >>= 1) ss += __shfl_xor(ss, off, 16);
    out[(size_t)node * NCLASS + c] = v - mx - logf(ss);
}

// ======================= fallback path (R3 atomic version) =================

__global__ void zero_kernel(float* __restrict__ h, float* __restrict__ out) {
    int i = blockIdx.x * 256 + threadIdx.x;
    if (i < N_NODES * NHID) h[i] = 0.f;
    if (i < N_NODES * NCLASS) out[i] = 0.f;
}

__global__ void gemm1_kernel(const float* __restrict__ x,
                             const float* __restrict__ W1,
                             float* __restrict__ s1) {
    int node = blockIdx.x * 4 + (threadIdx.x >> 6);
    int col  = threadIdx.x & 63;
    if (node >= N_NODES) return;
    const float* xr = x + (size_t)node * NFEAT;
    float sum = 0.f;
#pragma unroll 8
    for (int k = 0; k < NFEAT; ++k)
        sum = fmaf(xr[k], W1[k * NHID + col], sum);
    s1[(size_t)node * NHID + col] = sum;
}

__global__ void spmm1_kernel(const int* __restrict__ src, const int* __restrict__ dst,
                             const float* __restrict__ w, const float* __restrict__ s1,
                             float* __restrict__ h) {
    int e = blockIdx.x * 4 + (threadIdx.x >> 6);
    if (e >= N_EDGES) return;
    int lane = threadIdx.x & 63;
    int s = min(max(src[e], 0), N_NODES - 1);
    int d = min(max(dst[e], 0), N_NODES - 1);
    float v = w[e] * s1[(size_t)s * NHID + lane];
    atomicAdd(&h[(size_t)d * NHID + lane], v);
}

__global__ void bias_relu_kernel(float* __restrict__ h, const float* __restrict__ b1) {
    int i = blockIdx.x * 256 + threadIdx.x;
    if (i >= N_NODES * NHID) return;
    float v = h[i] + b1[i & (NHID - 1)];
    h[i] = v > 0.f ? v : 0.f;
}

__global__ void gemm2_kernel(const float* __restrict__ h,
                             const float* __restrict__ W2,
                             float* __restrict__ s2) {
    int node = blockIdx.x * 16 + (threadIdx.x >> 4);
    int col  = threadIdx.x & 15;
    if (node >= N_NODES) return;
    const float* hr = h + (size_t)node * NHID;
    float sum = 0.f;
#pragma unroll 8
    for (int k = 0; k < NHID; ++k)
        sum = fmaf(hr[k], W2[k * NCLASS + col], sum);
    s2[(size_t)node * NCLASS + col] = sum;
}

__global__ void spmm2_kernel(const int* __restrict__ src, const int* __restrict__ dst,
                             const float* __restrict__ w, const float* __restrict__ s2,
                             float* __restrict__ out) {
    int e = blockIdx.x * 16 + (threadIdx.x >> 4);
    if (e >= N_EDGES) return;
    int lane = threadIdx.x & 15;
    int s = min(max(src[e], 0), N_NODES - 1);
    int d = min(max(dst[e], 0), N_NODES - 1);
    float v = w[e] * s2[(size_t)s * NCLASS + lane];
    atomicAdd(&out[(size_t)d * NCLASS + lane], v);
}

__global__ void logsoftmax_kernel(float* __restrict__ out, const float* __restrict__ b2) {
    int n = blockIdx.x * 256 + threadIdx.x;
    if (n >= N_NODES) return;
    float v[NCLASS];
    float mx = -INFINITY;
#pragma unroll
    for (int c = 0; c < NCLASS; ++c) {
        v[c] = out[(size_t)n * NCLASS + c] + b2[c];
        mx = fmaxf(mx, v[c]);
    }
    float ssum = 0.f;
#pragma unroll
    for (int c = 0; c < NCLASS; ++c) ssum += expf(v[c] - mx);
    float ls = mx + logf(ssum);
#pragma unroll
    for (int c = 0; c < NCLASS; ++c) out[(size_t)n * NCLASS + c] = v[c] - ls;
}

// ======================= launch ============================================

extern "C" void kernel_launch(void* const* d_in, const int* in_sizes, int n_in,
                              void* d_out, int out_size, void* d_ws, size_t ws_size,
                              hipStream_t stream) {
    if (n_in != 8) return;
    const int expected[8] = { N_NODES * NFEAT, NFEAT * NHID, NHID,
                              NHID * NCLASS, NCLASS, N_EDGES, N_EDGES, N_EDGES };
    for (int i = 0; i < 8; ++i)
        if (in_sizes[i] != expected[i]) return;
    if (out_size != N_NODES * NCLASS) return;

    const float* x  = (const float*)d_in[0];
    const float* W1 = (const float*)d_in[1];
    const float* b1 = (const float*)d_in[2];
    const float* W2 = (const float*)d_in[3];
    const float* b2 = (const float*)d_in[4];
    const int* edge_src = (const int*)d_in[5];
    const int* edge_dst = (const int*)d_in[6];
    const float* edge_w = (const float*)d_in[7];
    float* out = (float*)d_out;

    const size_t S1_ELTS = (size_t)N_NODES * NHID;          // 3.2M
    const size_t CAP_WORDS = (size_t)NBINS * BIN_CAP * 2;   // int2 region, words
    const size_t NEW_WORDS = 2 * CAP_WORDS + 2 * (size_t)N_NODES + NBINS + 64;
    if (ws_size >= NEW_WORDS * 4) {
        int2*  csr_bin   = (int2*)d_ws;                      // slot A (16 MB)
        unsigned short* s1b = (unsigned short*)d_ws;          // aliases A[0,6.4MB)
        float* s2        = (float*)d_ws + S1_ELTS / 2;        // aliases A[6.4,9.6MB)
        int2*  csr_edge  = (int2*)((int*)d_ws + CAP_WORDS);
        int2*  row_range = (int2*)((int*)csr_edge + CAP_WORDS);
        int*   bin_cursor = (int*)row_range + 2 * N_NODES;

        // --- CSR build ---
        init_cursor_kernel<<<(NBINS + 255) / 256, 256, 0, stream>>>(bin_cursor);
        bin_scatter_kernel<<<K3_BLOCKS, 256, 0, stream>>>(
            edge_src, edge_dst, edge_w, bin_cursor, csr_bin);
        bin_csr_kernel<<<NBINS, 256, 0, stream>>>(
            bin_cursor, csr_bin, csr_edge, row_range);

        // --- layer 1 + fused layer-2 GEMM ---
        gemm1_tiled<<<(N_NODES + 63) / 64, 256, 0, stream>>>(x, W1, s1b);
        spmm1_fused_kernel<<<N_NODES / 16, 256, 0, stream>>>(
            row_range, csr_edge, (const uint2*)s1b, b1, W2, s2);
        // --- layer 2 aggregation + epilogue ---
        spmm2_csr_kernel<<<(N_NODES + 15) / 16, 256, 0, stream>>>(
            row_range, csr_edge, s2, b2, out);
        return;
    }

    // --- fallback: proven atomic path (25.6 MB ws) ---
    if (ws_size < 2 * S1_ELTS * sizeof(float)) return;
    float* s1 = (float*)d_ws;
    float* h  = s1 + S1_ELTS;
    float* s2 = s1;
    zero_kernel<<<(N_NODES * NHID + 255) / 256, 256, 0, stream>>>(h, out);
    gemm1_kernel<<<(N_NODES + 3) / 4, 256, 0, stream>>>(x, W1, s1);
    spmm1_kernel<<<(N_EDGES + 3) / 4, 256, 0, stream>>>(edge_src, edge_dst, edge_w, s1, h);
    bias_relu_kernel<<<(N_NODES * NHID + 255) / 256, 256, 0, stream>>>(h, b1);
    gemm2_kernel<<<(N_NODES + 15) / 16, 256, 0, stream>>>(h, W2, s2);
    spmm2_kernel<<<(N_EDGES + 15) / 16, 256, 0, stream>>>(edge_src, edge_dst, edge_w, s2, out);
    logsoftmax_kernel<<<(N_NODES + 255) / 256, 256, 0, stream>>>(out, b2);
}